// Round 4
// baseline (232.609 us; speedup 1.0000x reference)
//
#include <hip/hip_runtime.h>
#include <cmath>

#define F_IN 8
#define PER 12
#define FEAT 96   // F_IN*PER
#define HID 64
#define CAP 64    // bucket capacity per node (in-degree ~ Poisson(24); P(>=64) ~ 6e-12/node)
#define NB 8      // nodes per block in k_node

static inline size_t al256(size_t x) { return (x + 255) & ~(size_t)255; }

// ---------- bucket build: ONE atomic per edge ----------

__global__ void k_bucket(const int* __restrict__ src, const int* __restrict__ dst,
                         const float* __restrict__ attr,
                         int* __restrict__ cnt, int2* __restrict__ bucket, int e) {
    int i = blockIdx.x * 256 + threadIdx.x;
    if (i >= e) return;
    int d = dst[i];
    int pos = atomicAdd(&cnt[d], 1);
    if (pos < CAP) {   // clamp: overflow statistically impossible, but never corrupt memory
        int2 p;
        p.x = src[i];
        p.y = __float_as_int(attr[i]);
        bucket[(size_t)d * CAP + pos] = p;
    }
}

// ---------- per-node weighted degree -> dinv (no atomics) ----------

__global__ void k_dinv(const int* __restrict__ cnt, const int2* __restrict__ bucket,
                       float* __restrict__ dinv, int n) {
    int i = blockIdx.x * 256 + threadIdx.x;
    if (i >= n) return;
    int c = min(cnt[i], CAP);
    const int2* b = bucket + (size_t)i * CAP;
    float s = 1.0f;   // self-loop weight
    for (int e = 0; e < c; ++e) s += __int_as_float(b[e].y);
    dinv[i] = rsqrtf(s);
}

// ---------- fold weights: Mz=Wcz@Wlz_top, Mh=Wch@Wlh_top, biases, softmax(att) ----------
// M layout: [0..511]=Mz, [512..1023]=Mh, [1024..1087]=cz, [1088..1151]=ch, [1152..1163]=probs

__global__ void k_weights(const float* __restrict__ Wcz, const float* __restrict__ bcz,
                          const float* __restrict__ Wch, const float* __restrict__ bch,
                          const float* __restrict__ Wlz, const float* __restrict__ blz,
                          const float* __restrict__ Wlh, const float* __restrict__ blh,
                          const float* __restrict__ att, float* __restrict__ M) {
    int j = threadIdx.x;  // 64 threads
    for (int f = 0; f < F_IN; ++f) {
        float az = 0.f, ah = 0.f;
        for (int k = 0; k < HID; ++k) {
            az = fmaf(Wcz[f * HID + k], Wlz[k * HID + j], az);
            ah = fmaf(Wch[f * HID + k], Wlh[k * HID + j], ah);
        }
        M[f * HID + j] = az;
        M[512 + f * HID + j] = ah;
    }
    float cz = blz[j], ch = blh[j];
    for (int k = 0; k < HID; ++k) {
        cz = fmaf(bcz[k], Wlz[k * HID + j], cz);
        ch = fmaf(bch[k], Wlh[k * HID + j], ch);
    }
    M[1024 + j] = cz;
    M[1088 + j] = ch;
    if (j < PER) {
        float s = 0.f;
        for (int t = 0; t < PER; ++t) s += expf(att[t]);
        M[1152 + j] = expf(att[j]) / s;
    }
}

// ---------- gather: Xp[n,:] = dinv[n]*(dinv[n]*X[n,:] + sum_e attr*dinv[src]*X[src,:]) ----------
// 32 threads/node (24 active), wave-aligned groups; unroll-4 with int4 bucket loads.
// OUTPUT ALIASES THE BUCKET: node i's 384B Xp overwrites its own 512B slot (only this
// node's lanes, all in ONE wave, touch slot i, and every bucket read is a data-dep of
// the store) -> keeps workspace at ~26 MB, no extra Xp buffer.

__global__ __launch_bounds__(256) void k_gather(const int* __restrict__ cnt,
                                                int2* __restrict__ bucket,
                                                const float* __restrict__ dinv,
                                                const float4* __restrict__ X4,
                                                int n) {
    int i = blockIdx.x * 256 + threadIdx.x;
    int node = i >> 5;
    int g = i & 31;
    if (node >= n || g >= 24) return;

    float dv = dinv[node];
    float4 self = X4[(size_t)node * 24 + g];
    float4 acc = make_float4(0.f, 0.f, 0.f, 0.f);
    int c = min(cnt[node], CAP);
    const int4* B4 = (const int4*)(bucket + (size_t)node * CAP);  // 2 edges per int4

    int e = 0;
    for (; e + 4 <= c; e += 4) {
        int4 q0 = B4[e >> 1];
        int4 q1 = B4[(e >> 1) + 1];
        float w0 = __int_as_float(q0.y) * dinv[q0.x];
        float w1 = __int_as_float(q0.w) * dinv[q0.z];
        float w2 = __int_as_float(q1.y) * dinv[q1.x];
        float w3 = __int_as_float(q1.w) * dinv[q1.z];
        float4 v0 = X4[(size_t)q0.x * 24 + g];
        float4 v1 = X4[(size_t)q0.z * 24 + g];
        float4 v2 = X4[(size_t)q1.x * 24 + g];
        float4 v3 = X4[(size_t)q1.z * 24 + g];
        acc.x = fmaf(w0, v0.x, fmaf(w1, v1.x, fmaf(w2, v2.x, fmaf(w3, v3.x, acc.x))));
        acc.y = fmaf(w0, v0.y, fmaf(w1, v1.y, fmaf(w2, v2.y, fmaf(w3, v3.y, acc.y))));
        acc.z = fmaf(w0, v0.z, fmaf(w1, v1.z, fmaf(w2, v2.z, fmaf(w3, v3.z, acc.z))));
        acc.w = fmaf(w0, v0.w, fmaf(w1, v1.w, fmaf(w2, v2.w, fmaf(w3, v3.w, acc.w))));
    }
    const int2* B = (const int2*)B4;
    for (; e < c; ++e) {
        int2 p = B[e];
        float w = __int_as_float(p.y) * dinv[p.x];
        float4 v = X4[(size_t)p.x * 24 + g];
        acc.x = fmaf(w, v.x, acc.x);
        acc.y = fmaf(w, v.y, acc.y);
        acc.z = fmaf(w, v.z, acc.z);
        acc.w = fmaf(w, v.w, acc.w);
    }

    float4 r;
    r.x = dv * fmaf(dv, self.x, acc.x);
    r.y = dv * fmaf(dv, self.y, acc.y);
    r.z = dv * fmaf(dv, self.z, acc.z);
    r.w = dv * fmaf(dv, self.w, acc.w);
    ((float4*)bucket)[(size_t)node * 32 + g] = r;   // alias: slot i, first 384B
}

// ---------- per-node GRU over 12 periods + attention accum + relu + readout ----------
// Block = 256 threads = NB(8) nodes. Xp read from the aliased bucket region (stride 512B).

__global__ __launch_bounds__(256) void k_node(const float4* __restrict__ Xp4,
                                              const float* __restrict__ M,
                                              const float* __restrict__ Wout,
                                              const float* __restrict__ bout,
                                              float* __restrict__ out, int n) {
    __shared__ float s_xp[NB][FEAT];
    __shared__ float s_acc[NB][HID];
    int t = threadIdx.x;
    int node0 = blockIdx.x * NB;

    if (t < NB * 24) {
        int ln = t / 24;
        int g = t - ln * 24;
        int node = node0 + ln;
        if (node < n)
            ((float4*)&s_xp[ln][0])[g] = Xp4[(size_t)node * 32 + g];
    }
    __syncthreads();

    // GRU: 4 waves, wave handles nodes 2w, 2w+1; lane = hidden unit.
    {
        int lane = t & 63;
        int wv = t >> 6;
        float mz[F_IN], mh[F_IN];
#pragma unroll
        for (int f = 0; f < F_IN; ++f) {
            mz[f] = M[f * HID + lane];
            mh[f] = M[512 + f * HID + lane];
        }
        float cz = M[1024 + lane], ch = M[1088 + lane];
        float pr[PER];
#pragma unroll
        for (int tt = 0; tt < PER; ++tt) pr[tt] = M[1152 + tt];

#pragma unroll
        for (int q = 0; q < 2; ++q) {
            int ln = wv * 2 + q;
            float acc = 0.f;
#pragma unroll
            for (int tt = 0; tt < PER; ++tt) {
                float xz = cz, xh = ch;
#pragma unroll
                for (int f = 0; f < F_IN; ++f) {
                    float xv = s_xp[ln][f * PER + tt];
                    xz = fmaf(xv, mz[f], xz);
                    xh = fmaf(xv, mh[f], xh);
                }
                float z = 1.f / (1.f + __expf(-xz));
                float h = tanhf(xh);
                acc += pr[tt] * (1.f - z) * h;
            }
            s_acc[ln][lane] = fmaxf(acc, 0.f);
        }
    }
    __syncthreads();

    // readout: 96 threads, (node, period) -> out
    if (t < NB * PER) {
        int ln = t / PER;
        int pp = t - ln * PER;
        int node = node0 + ln;
        if (node < n) {
            float o = bout[pp];
#pragma unroll
            for (int j = 0; j < HID; ++j) o = fmaf(s_acc[ln][j], Wout[j * PER + pp], o);
            out[(size_t)node * PER + pp] = o;
        }
    }
}

// ---------- launch ----------

extern "C" void kernel_launch(void* const* d_in, const int* in_sizes, int n_in,
                              void* d_out, int out_size, void* d_ws, size_t ws_size,
                              hipStream_t stream) {
    const float* X     = (const float*)d_in[0];
    const int*   ei    = (const int*)d_in[1];
    const float* attr  = (const float*)d_in[2];
    const float* att   = (const float*)d_in[3];
    const float* Wcz   = (const float*)d_in[4];
    const float* bcz   = (const float*)d_in[5];
    // d_in[6], d_in[7] = Wcr, bcr -- dead (H0 == 0 kills the R path)
    const float* Wch   = (const float*)d_in[8];
    const float* bch   = (const float*)d_in[9];
    const float* Wlz   = (const float*)d_in[10];
    const float* blz   = (const float*)d_in[11];
    // d_in[12], d_in[13] = Wlr, blr -- dead
    const float* Wlh   = (const float*)d_in[14];
    const float* blh   = (const float*)d_in[15];
    const float* Wout  = (const float*)d_in[16];
    const float* bout  = (const float*)d_in[17];
    float* out = (float*)d_out;

    const int N = in_sizes[0] / FEAT;
    const int E = in_sizes[2];
    const int* src = ei;
    const int* dst = ei + E;

    // workspace layout (~26 MB); Xp aliases bucket
    char* base = (char*)d_ws;
    size_t o = 0;
    int*   cnt    = (int*)  (base + o); o += al256((size_t)N * 4);
    float* dinv   = (float*)(base + o); o += al256((size_t)N * 4);
    float* M      = (float*)(base + o); o += al256(1280 * 4);
    int2*  bucket = (int2*) (base + o); o += al256((size_t)N * CAP * 8);

    hipMemsetAsync(cnt, 0, (size_t)N * 4, stream);
    k_bucket<<<(E + 255) / 256, 256, 0, stream>>>(src, dst, attr, cnt, bucket, E);
    k_dinv<<<(N + 255) / 256, 256, 0, stream>>>(cnt, bucket, dinv, N);
    k_weights<<<1, 64, 0, stream>>>(Wcz, bcz, Wch, bch, Wlz, blz, Wlh, blh, att, M);

    int gthreads = N * 32;
    k_gather<<<(gthreads + 255) / 256, 256, 0, stream>>>(cnt, bucket, dinv, (const float4*)X, N);

    k_node<<<(N + NB - 1) / NB, 256, 0, stream>>>((const float4*)bucket, M, Wout, bout, out, N);
}